// Round 5
// baseline (208.685 us; speedup 1.0000x reference)
//
#include <hip/hip_runtime.h>
#include <math.h>

// Problem constants
#define BB   4
#define CC   128
#define HH   64
#define WW   64
#define OUTC 128
#define LW   5
#define KK   25   // LW*LW
#define NCS  2    // c-split count (compile-time)
#define CPER 64   // channels per split

// ---------------------------------------------------------------------------
// Kernel 0: w2stH[c][o] = bf16( sum_{r=0..3} w2[o, c*4+r] )
// ---------------------------------------------------------------------------
__global__ void prep_w2_kernel(const float* __restrict__ w2,
                               unsigned short* __restrict__ w2stH) {
    int i = blockIdx.x * 256 + threadIdx.x;   // i < 128*128
    int o = i >> 7;
    int c = i & 127;            // consecutive threads -> consecutive c (16B stride reads)
    const float* p = w2 + o * (4 * CC) + c * 4;
    float v = p[0] + p[1] + p[2] + p[3];
    unsigned int u = __float_as_uint(v);
    u += 0x7fffu + ((u >> 16) & 1u);          // RNE to bf16
    w2stH[c * OUTC + o] = (unsigned short)(u >> 16);
}

// ---------------------------------------------------------------------------
// Kernel 1: conv1 3x3 SAME. Block = (b, 4-row tile, c-half cs, kc-group of 5).
// grid: 4 * 16 * 2 * 5 = 640 blocks of 256 threads. Compile-time bounds.
// x staged in LDS 8 channels at a time (6 rows, zero vertical halo); weights
// via wave-uniform s_load; 45 FMA per 9 conflict-free LDS reads.
// Output: per-cs partial slabs kwsP[cs][b][kc][h][w], plain stores.
// ---------------------------------------------------------------------------
__global__ __launch_bounds__(256) void conv1_kernel(
        const float* __restrict__ x,
        const float* __restrict__ w1,
        float* __restrict__ kwsP) {
    __shared__ float xt[6 * 8 * 64];   // [r][ci][col], 12 KB

    int bid = blockIdx.x;
    int kcg  = bid % 5;
    int rest = bid / 5;
    int cs   = rest & 1;
    rest >>= 1;
    int ht = rest & 15;
    int b  = rest >> 4;

    int t  = threadIdx.x;
    int w  = t & 63;
    int th = t >> 6;
    int h  = ht * 4 + th;

    float ml = (w > 0)  ? 1.f : 0.f;
    float mr = (w < 63) ? 1.f : 0.f;
    int wl = (w > 0)  ? w - 1 : 0;
    int wr = (w < 63) ? w + 1 : 63;

    float acc[5] = {0.f, 0.f, 0.f, 0.f, 0.f};

    const float* xb = x + ((size_t)b * CC + cs * CPER) * (HH * WW);
    const float* wb = w1 + (size_t)(kcg * 5) * (CC * 9) + (size_t)(cs * CPER) * 9;

    for (int c0 = 0; c0 < CPER; c0 += 8) {
        __syncthreads();   // previous iteration's readers done
        // stage 8 channels x 6 rows (vertical halo zero-filled)
        // each wave covers one (r,ci) pair x 64 cols: perfectly coalesced
        for (int i = t; i < 3072; i += 256) {
            int r   = i >> 9;
            int ci  = (i >> 6) & 7;
            int col = i & 63;
            int y = ht * 4 - 1 + r;
            float v = 0.f;
            if (y >= 0 && y < HH)
                v = xb[(size_t)(c0 + ci) * (HH * WW) + y * WW + col];
            xt[i] = v;
        }
        __syncthreads();

        #pragma unroll
        for (int ci = 0; ci < 8; ++ci) {
            const float* xr = &xt[ci * 64];
            float xv0 = xr[(th + 0) * 512 + wl] * ml;
            float xv1 = xr[(th + 0) * 512 + w];
            float xv2 = xr[(th + 0) * 512 + wr] * mr;
            float xv3 = xr[(th + 1) * 512 + wl] * ml;
            float xv4 = xr[(th + 1) * 512 + w];
            float xv5 = xr[(th + 1) * 512 + wr] * mr;
            float xv6 = xr[(th + 2) * 512 + wl] * ml;
            float xv7 = xr[(th + 2) * 512 + w];
            float xv8 = xr[(th + 2) * 512 + wr] * mr;

            const float* wp = wb + (size_t)(c0 + ci) * 9;
            #pragma unroll
            for (int kci = 0; kci < 5; ++kci) {
                const float* wk = wp + (size_t)kci * (CC * 9);
                acc[kci] += wk[0] * xv0 + wk[1] * xv1 + wk[2] * xv2
                          + wk[3] * xv3 + wk[4] * xv4 + wk[5] * xv5
                          + wk[6] * xv6 + wk[7] * xv7 + wk[8] * xv8;
            }
        }
    }

    float* kb = kwsP + ((size_t)(cs * BB + b) * KK + kcg * 5) * (HH * WW)
                     + h * WW + w;
    #pragma unroll
    for (int kci = 0; kci < 5; ++kci)
        kb[(size_t)kci * (HH * WW)] = acc[kci];
}

// ---------------------------------------------------------------------------
// Kernel 2: fused softmax + local attention + (C->OUT) GEMM + 2x2-replicated
//           output write. 16-pixel blocks: grid 4*64*4 = 1024, 256 threads.
// ---------------------------------------------------------------------------
__global__ __launch_bounds__(256) void fused_kernel(
        const float* __restrict__ x,
        const unsigned short* __restrict__ w2stH,
        const float* __restrict__ b1,
        const float* __restrict__ b2,
        const float* __restrict__ kwsP,
        float* __restrict__ out) {
    __shared__ float pk[KK * 16];                              // 1.6 KB
    __shared__ float sK[CC * 16];                              // 8 KB
    __shared__ __align__(16) char ubuf[32 * 1024];             // 32 KB union
    float*          xld  = (float*)ubuf;           // phase 2: 32c x 5r x 25
    unsigned short* wchH = (unsigned short*)ubuf;  // phase 3: w2stH copy

    int bid = blockIdx.x;
    int wq = bid & 3;
    int h  = (bid >> 2) & 63;
    int b  = bid >> 8;
    int t  = threadIdx.x;

    // ---- Phase 1: sum NCS conv1 partials + bias -> logits ----
    for (int i = t; i < KK * 16; i += 256) {
        int kk = i >> 4, px = i & 15;
        size_t o0 = ((size_t)(0 * BB + b) * KK + kk) * (HH * WW)
                    + h * WW + wq * 16 + px;
        size_t o1 = ((size_t)(1 * BB + b) * KK + kk) * (HH * WW)
                    + h * WW + wq * 16 + px;
        pk[i] = kwsP[o0] + kwsP[o1] + b1[kk];
    }
    __syncthreads();

    if (t < 16) {
        float mx = -1e30f;
        for (int k = 0; k < KK; ++k) mx = fmaxf(mx, pk[k * 16 + t]);
        float s = 0.f;
        for (int k = 0; k < KK; ++k) {
            float e = __expf(pk[k * 16 + t] - mx);
            pk[k * 16 + t] = e;
            s += e;
        }
        float inv = 1.f / s;
        for (int k = 0; k < KK; ++k) pk[k * 16 + t] *= inv;
    }
    __syncthreads();

    // ---- Phase 2: s[c][px] = sum_tap p[tap][px] * xpad[c][...] ----
    // thread = (pp = t&7 -> pixels {2pp,2pp+1}, clane = t>>3 in 0..31)
    int pp = t & 7, clane = t >> 3;
    float p0[KK], p1[KK];
    #pragma unroll
    for (int k = 0; k < KK; ++k) {
        p0[k] = pk[k * 16 + 2 * pp];
        p1[k] = pk[k * 16 + 2 * pp + 1];
    }

    const float* xb = x + (size_t)(b * CC) * (HH * WW);
    for (int ch = 0; ch < 4; ++ch) {
        __syncthreads();
        // stage 32 c x 5 rows x 20 cols at row stride 25 (odd -> no even-bank
        // aliasing). i -> (c = i/160, di = (i%160)>>5, col = i&31), col<20.
        for (int i = t; i < 5120; i += 256) {
            int c   = i / 160;
            int rem = i - c * 160;
            int di  = rem >> 5;
            int col = rem & 31;
            if (col < 20) {
                int y  = h + di - 2;
                int xc = wq * 16 + col - 2;
                float v = 0.f;
                if (y >= 0 && y < HH && xc >= 0 && xc < WW)
                    v = xb[(size_t)(ch * 32 + c) * (HH * WW) + y * WW + xc];
                xld[c * 125 + di * 25 + col] = v;
            }
        }
        __syncthreads();

        float a0 = 0.f, a1 = 0.f;
        const float* xr = &xld[clane * 125];
        #pragma unroll
        for (int di = 0; di < 5; ++di) {
            float xv[6];
            #pragma unroll
            for (int j = 0; j < 6; ++j) xv[j] = xr[di * 25 + 2 * pp + j];
            #pragma unroll
            for (int dj = 0; dj < 5; ++dj) {
                a0 += p0[di * 5 + dj] * xv[dj];
                a1 += p1[di * 5 + dj] * xv[dj + 1];
            }
        }
        int c = ch * 32 + clane;
        sK[c * 16 + 2 * pp]     = a0;
        sK[c * 16 + 2 * pp + 1] = a1;
    }

    // ---- Phase 3: V[o][px] = b2[o] + sum_c s[c][px] * w2s[c][o] ----
    __syncthreads();   // xld dead; reuse ubuf as wchH
    {
        uint4* dst = (uint4*)wchH;
        const uint4* src = (const uint4*)w2stH;
        for (int i = t; i < 2048; i += 256) dst[i] = src[i];
    }
    __syncthreads();

    int slot = t & 3, og = t >> 2;   // 4 px x 2 o per thread
    float2 bv = *(const float2*)(b2 + og * 2);
    float acc[8];
    acc[0] = bv.x; acc[1] = bv.x; acc[2] = bv.x; acc[3] = bv.x;
    acc[4] = bv.y; acc[5] = bv.y; acc[6] = bv.y; acc[7] = bv.y;

    #pragma unroll 4
    for (int cc = 0; cc < CC; ++cc) {
        float4 s4 = *(const float4*)&sK[cc * 16 + slot * 4];
        unsigned int wu = *(const unsigned int*)&wchH[cc * OUTC + og * 2];
        float w0 = __uint_as_float(wu << 16);
        float w1 = __uint_as_float(wu & 0xffff0000u);
        acc[0] += w0 * s4.x; acc[1] += w0 * s4.y;
        acc[2] += w0 * s4.z; acc[3] += w0 * s4.w;
        acc[4] += w1 * s4.x; acc[5] += w1 * s4.y;
        acc[6] += w1 * s4.z; acc[7] += w1 * s4.w;
    }

    // ---- write: 2x2-replicated, float4 pairs ----
    float* ob = out + (size_t)(b * OUTC) * (4 * HH * WW);
    int y0   = 2 * h;
    int colb = 2 * (wq * 16 + slot * 4);   // 8 consecutive floats
    #pragma unroll
    for (int oi = 0; oi < 2; ++oi) {
        int o = og * 2 + oi;
        float4 lo = make_float4(acc[oi*4+0], acc[oi*4+0], acc[oi*4+1], acc[oi*4+1]);
        float4 hi = make_float4(acc[oi*4+2], acc[oi*4+2], acc[oi*4+3], acc[oi*4+3]);
        float* r0 = ob + ((size_t)o * (2 * HH) + y0) * (2 * WW) + colb;
        *(float4*)(r0)              = lo;
        *(float4*)(r0 + 4)          = hi;
        *(float4*)(r0 + 2 * WW)     = lo;
        *(float4*)(r0 + 2 * WW + 4) = hi;
    }
}

// ---------------------------------------------------------------------------
extern "C" void kernel_launch(void* const* d_in, const int* in_sizes, int n_in,
                              void* d_out, int out_size, void* d_ws, size_t ws_size,
                              hipStream_t stream) {
    const float* x  = (const float*)d_in[0];
    const float* w1 = (const float*)d_in[1];
    const float* b1 = (const float*)d_in[2];
    const float* w2 = (const float*)d_in[3];
    const float* b2 = (const float*)d_in[4];
    float* out = (float*)d_out;

    const size_t slab = (size_t)BB * KK * HH * WW;        // 409600 floats/cs
    float* kwsP = (float*)d_ws;                           // 2 slabs: 3.28 MB
    unsigned short* w2stH = (unsigned short*)(kwsP + NCS * slab);  // 32 KB

    prep_w2_kernel<<<64, 256, 0, stream>>>(w2, w2stH);
    conv1_kernel<<<BB * 16 * NCS * 5, 256, 0, stream>>>(x, w1, kwsP);
    fused_kernel<<<BB * HH * 4, 256, 0, stream>>>(x, w2stH, b1, b2, kwsP, out);
}

// Round 6
// 149.059 us; speedup vs baseline: 1.4000x; 1.4000x over previous
//
#include <hip/hip_runtime.h>
#include <math.h>

// Problem constants
#define BB   4
#define CC   128
#define HH   64
#define WW   64
#define OUTC 128
#define LW   5
#define KK   25   // LW*LW
#define NCS  4    // c-split count
#define CPER 32   // channels per split

// ---------------------------------------------------------------------------
// Kernel 0: w2stH[c][o] = bf16( sum_{r=0..3} w2[o, c*4+r] )  (c-major)
// ---------------------------------------------------------------------------
__global__ void prep_w2_kernel(const float* __restrict__ w2,
                               unsigned short* __restrict__ w2stH) {
    int i = blockIdx.x * 256 + threadIdx.x;   // i < 128*128
    int o = i >> 7;
    int c = i & 127;
    const float* p = w2 + o * (4 * CC) + c * 4;
    float v = p[0] + p[1] + p[2] + p[3];
    unsigned int u = __float_as_uint(v);
    u += 0x7fffu + ((u >> 16) & 1u);          // RNE to bf16
    w2stH[c * OUTC + o] = (unsigned short)(u >> 16);
}

// ---------------------------------------------------------------------------
// Kernel 1: conv1 3x3 SAME. No LDS, no barriers: pure load/FMA stream.
// grid: 4(b) * 8(ht of 8 rows) * 4(cs) * 5(kcg) = 640 blocks, 256 threads.
// thread: 2 px (cols 2w2, 2w2+1) of row ht*8 + (t>>5). Per c: 9 VMEM
// (3x float2 + 6 edge b32, L1/L2-hit) feed 90 FMA with wave-uniform s_load
// weights. Output: per-cs partial slabs kwsP[cs][b][kc][h][w].
// ---------------------------------------------------------------------------
__global__ __launch_bounds__(256) void conv1_kernel(
        const float* __restrict__ x,
        const float* __restrict__ w1,
        float* __restrict__ kwsP) {
    int bid = blockIdx.x;
    int kcg  = bid % 5;
    int rest = bid / 5;
    int cs   = rest & 3;
    rest >>= 2;
    int ht = rest & 7;
    int b  = rest >> 3;

    int t  = threadIdx.x;
    int w2i = t & 31;
    int r   = t >> 5;
    int h   = ht * 8 + r;
    int col0 = 2 * w2i;

    float mt = (h > 0)       ? 1.f : 0.f;
    float mb = (h < HH - 1)  ? 1.f : 0.f;
    float ml = (col0 > 0)    ? 1.f : 0.f;
    float mr = (col0 + 2 < WW) ? 1.f : 0.f;
    int y0 = (h > 0) ? h - 1 : 0;
    int y2 = (h < HH - 1) ? h + 1 : HH - 1;
    int cl = (col0 > 0) ? col0 - 1 : 0;
    int cr = (col0 + 2 < WW) ? col0 + 2 : WW - 1;

    float acc[5][2];
    #pragma unroll
    for (int k = 0; k < 5; ++k) { acc[k][0] = 0.f; acc[k][1] = 0.f; }

    const float* xb = x + ((size_t)b * CC + cs * CPER) * (HH * WW);
    const float* wb = w1 + ((size_t)(kcg * 5) * CC + cs * CPER) * 9;

    #pragma unroll 2
    for (int c = 0; c < CPER; ++c) {
        const float* xc = xb + c * (HH * WW);
        const float* r0p = xc + y0 * WW;
        const float* r1p = xc + h  * WW;
        const float* r2p = xc + y2 * WW;

        float2 v0 = *(const float2*)(r0p + col0);
        float2 v1 = *(const float2*)(r1p + col0);
        float2 v2 = *(const float2*)(r2p + col0);
        float l0 = r0p[cl], l1 = r1p[cl], l2 = r2p[cl];
        float q0 = r0p[cr], q1 = r1p[cr], q2 = r2p[cr];

        // fold row masks into values (row0 *= mt, row2 *= mb), col masks into edges
        v0.x *= mt; v0.y *= mt; l0 *= mt * ml; q0 *= mt * mr;
        v1.x *= 1.f; l1 *= ml; q1 *= mr;
        v2.x *= mb; v2.y *= mb; l2 *= mb * ml; q2 *= mb * mr;

        const float* wc = wb + (size_t)c * 9;
        #pragma unroll
        for (int kci = 0; kci < 5; ++kci) {
            const float* wk = wc + (size_t)kci * (CC * 9);
            float w0 = wk[0], w1v = wk[1], w2v = wk[2];
            float w3 = wk[3], w4v = wk[4], w5v = wk[5];
            float w6 = wk[6], w7v = wk[7], w8v = wk[8];
            acc[kci][0] += l0   * w0 + v0.x * w1v + v0.y * w2v
                         + l1   * w3 + v1.x * w4v + v1.y * w5v
                         + l2   * w6 + v2.x * w7v + v2.y * w8v;
            acc[kci][1] += v0.x * w0 + v0.y * w1v + q0   * w2v
                         + v1.x * w3 + v1.y * w4v + q1   * w5v
                         + v2.x * w6 + v2.y * w7v + q2   * w8v;
        }
    }

    float* kb = kwsP + ((size_t)(cs * BB + b) * KK + kcg * 5) * (HH * WW)
                     + h * WW + col0;
    #pragma unroll
    for (int kci = 0; kci < 5; ++kci)
        *(float2*)(kb + (size_t)kci * (HH * WW)) = make_float2(acc[kci][0], acc[kci][1]);
}

// ---------------------------------------------------------------------------
// Kernel 2: fused softmax + local attention + (C->OUT) GEMM + 2x2-replicated
//           output write. 16-pixel blocks: grid 4*64*4 = 1024, 256 threads.
// LDS ~17.3 KB; phase-3 weights read straight from global (L1-resident).
// ---------------------------------------------------------------------------
__global__ __launch_bounds__(256) void fused_kernel(
        const float* __restrict__ x,
        const unsigned short* __restrict__ w2stH,
        const float* __restrict__ b1,
        const float* __restrict__ b2,
        const float* __restrict__ kwsP,
        float* __restrict__ out) {
    __shared__ float pk[KK * 16];        // softmax probs            (1.6 KB)
    __shared__ float xld[16 * 5 * 24];   // x tile, 16c x 5r x 20+pad (7.7 KB)
    __shared__ float sK[CC * 16];        // attention out s[c][px]    (8 KB)

    int bid = blockIdx.x;
    int wq = bid & 3;
    int h  = (bid >> 2) & 63;
    int b  = bid >> 8;
    int t  = threadIdx.x;

    // ---- Phase 1: sum NCS conv1 partials + bias -> logits ----
    for (int i = t; i < KK * 16; i += 256) {
        int kk = i >> 4, px = i & 15;
        size_t o0 = ((size_t)b * KK + kk) * (HH * WW) + h * WW + wq * 16 + px;
        const size_t sl = (size_t)BB * KK * HH * WW;
        pk[i] = kwsP[o0] + kwsP[o0 + sl] + kwsP[o0 + 2 * sl] + kwsP[o0 + 3 * sl]
              + b1[kk];
    }
    __syncthreads();

    if (t < 16) {
        float mx = -1e30f;
        for (int k = 0; k < KK; ++k) mx = fmaxf(mx, pk[k * 16 + t]);
        float s = 0.f;
        for (int k = 0; k < KK; ++k) {
            float e = __expf(pk[k * 16 + t] - mx);
            pk[k * 16 + t] = e;
            s += e;
        }
        float inv = 1.f / s;
        for (int k = 0; k < KK; ++k) pk[k * 16 + t] *= inv;
    }
    __syncthreads();

    // ---- Phase 2: s[c][px] = sum_tap p[tap][px] * xpad[c][...] ----
    // thread = (px = t&15, clane = t>>4 in 0..15); c-chunks of 16. (R4-proven)
    int px = t & 15, clane = t >> 4;

    const float* xb = x + (size_t)(b * CC) * (HH * WW);
    for (int ch = 0; ch < 8; ++ch) {
        __syncthreads();
        for (int i = t; i < 1600; i += 256) {
            int c   = i / 100;
            int rem = i - c * 100;
            int di  = rem / 20;
            int col = rem - di * 20;
            int y  = h + di - 2;
            int xc = wq * 16 + col - 2;
            float v = 0.f;
            if (y >= 0 && y < HH && xc >= 0 && xc < WW)
                v = xb[(size_t)(ch * 16 + c) * (HH * WW) + y * WW + xc];
            xld[(c * 5 + di) * 24 + col] = v;
        }
        __syncthreads();

        float a = 0.f;
        const float* xr = &xld[clane * 120];
        #pragma unroll
        for (int di = 0; di < 5; ++di) {
            float xv[5];
            #pragma unroll
            for (int j = 0; j < 5; ++j) xv[j] = xr[di * 24 + px + j];
            #pragma unroll
            for (int dj = 0; dj < 5; ++dj)
                a += pk[(di * 5 + dj) * 16 + px] * xv[dj];   // pk: broadcast read
        }
        sK[(ch * 16 + clane) * 16 + px] = a;
    }
    __syncthreads();

    // ---- Phase 3: V[o][px] = b2[o] + sum_c s[c][px] * w2s[c][o] ----
    // thread = (slot = t&7 -> 2 px, og = t>>3 -> 4 o). sK via b64 broadcast,
    // weights via global b64 (bf16 x4, L1-resident).
    int slot = t & 7, og = t >> 3;
    float4 bv = *(const float4*)(b2 + og * 4);
    float acc[8];   // [oi][p]
    acc[0] = bv.x; acc[1] = bv.x;
    acc[2] = bv.y; acc[3] = bv.y;
    acc[4] = bv.z; acc[5] = bv.z;
    acc[6] = bv.w; acc[7] = bv.w;

    const uint2* wg = (const uint2*)(w2stH) + (og);   // w2stH[cc*128 + og*4]
    #pragma unroll 8
    for (int cc = 0; cc < CC; ++cc) {
        float2 s2 = *(const float2*)&sK[cc * 16 + slot * 2];
        uint2 wu = wg[cc * 32];
        float w0 = __uint_as_float(wu.x << 16);
        float w1 = __uint_as_float(wu.x & 0xffff0000u);
        float w2 = __uint_as_float(wu.y << 16);
        float w3 = __uint_as_float(wu.y & 0xffff0000u);
        acc[0] += w0 * s2.x; acc[1] += w0 * s2.y;
        acc[2] += w1 * s2.x; acc[3] += w1 * s2.y;
        acc[4] += w2 * s2.x; acc[5] += w2 * s2.y;
        acc[6] += w3 * s2.x; acc[7] += w3 * s2.y;
    }

    // ---- write: px pair {2*slot, 2*slot+1} -> one float4 per o per row ----
    float* ob = out + (size_t)(b * OUTC) * (4 * HH * WW);
    int y0   = 2 * h;
    int colb = 2 * (wq * 16 + slot * 2);   // 4 consecutive floats
    #pragma unroll
    for (int oi = 0; oi < 4; ++oi) {
        int o = og * 4 + oi;
        float4 q = make_float4(acc[oi*2], acc[oi*2], acc[oi*2+1], acc[oi*2+1]);
        float* r0 = ob + ((size_t)o * (2 * HH) + y0) * (2 * WW) + colb;
        *(float4*)(r0)          = q;
        *(float4*)(r0 + 2 * WW) = q;
    }
}

// ---------------------------------------------------------------------------
extern "C" void kernel_launch(void* const* d_in, const int* in_sizes, int n_in,
                              void* d_out, int out_size, void* d_ws, size_t ws_size,
                              hipStream_t stream) {
    const float* x  = (const float*)d_in[0];
    const float* w1 = (const float*)d_in[1];
    const float* b1 = (const float*)d_in[2];
    const float* w2 = (const float*)d_in[3];
    const float* b2 = (const float*)d_in[4];
    float* out = (float*)d_out;

    const size_t slab = (size_t)BB * KK * HH * WW;        // 409600 floats/cs
    float* kwsP = (float*)d_ws;                           // 4 slabs: 6.55 MB
    unsigned short* w2stH = (unsigned short*)(kwsP + NCS * slab);  // 32 KB

    prep_w2_kernel<<<64, 256, 0, stream>>>(w2, w2stH);
    conv1_kernel<<<BB * 8 * NCS * 5, 256, 0, stream>>>(x, w1, kwsP);
    fused_kernel<<<BB * HH * 4, 256, 0, stream>>>(x, w2stH, b1, b2, kwsP, out);
}

// Round 7
// 135.570 us; speedup vs baseline: 1.5393x; 1.0995x over previous
//
#include <hip/hip_runtime.h>
#include <math.h>

// Problem constants
#define BB   4
#define CC   128
#define HH   64
#define WW   64
#define OUTC 128
#define LW   5
#define KK   25   // LW*LW
#define NCS  4    // conv1 c-split count
#define CPER 32   // channels per split

typedef __attribute__((ext_vector_type(8))) short short8;   // 8 bf16
typedef __attribute__((ext_vector_type(4))) float floatx4;  // MFMA acc

__device__ __forceinline__ unsigned short f32_to_bf16(float v) {
    unsigned int u = __float_as_uint(v);
    u += 0x7fffu + ((u >> 16) & 1u);          // RNE
    return (unsigned short)(u >> 16);
}

// ---------------------------------------------------------------------------
// Kernel 0 (prep): two jobs in one launch.
//  i < 16384:  w2o[o][c] = bf16( sum_{r} w2[o, c*4+r] )      (o-major!)
//  else:       w1t[kcg][c][kci][j] = w1[(kcg*5+kci)][c][j]   (45 contig / c)
// ---------------------------------------------------------------------------
__global__ void prep_kernel(const float* __restrict__ w2,
                            const float* __restrict__ w1,
                            unsigned short* __restrict__ w2o,
                            float* __restrict__ w1t) {
    int i = blockIdx.x * 256 + threadIdx.x;
    if (i < 16384) {
        int o = i >> 7, c = i & 127;
        const float* p = w2 + o * (4 * CC) + c * 4;
        w2o[o * CC + c] = f32_to_bf16(p[0] + p[1] + p[2] + p[3]);
    } else if (i < 16384 + 28800) {
        int j  = i - 16384;
        int jj = j % 9;
        int r  = j / 9;
        int kci = r % 5;  r /= 5;
        int c   = r % 128;
        int kcg = r / 128;
        w1t[j] = w1[(size_t)((kcg * 5 + kci) * CC + c) * 9 + jj];
    }
}

// ---------------------------------------------------------------------------
// Kernel 1: conv1 3x3 SAME. No LDS/barriers; weights CONTIGUOUS 45 dwords/c
// via w1t -> bulk s_load_dwordx16. grid 4*8*4*5 = 640 blocks, 256 threads.
// thread: 2 px. Output: per-cs partial slabs kwsP[cs][b][kc][h][w].
// ---------------------------------------------------------------------------
__global__ __launch_bounds__(256) void conv1_kernel(
        const float* __restrict__ x,
        const float* __restrict__ w1t,
        float* __restrict__ kwsP) {
    int bid = blockIdx.x;
    int kcg  = bid % 5;
    int rest = bid / 5;
    int cs   = rest & 3;
    rest >>= 2;
    int ht = rest & 7;
    int b  = rest >> 3;

    int t  = threadIdx.x;
    int w2i = t & 31;
    int r   = t >> 5;
    int h   = ht * 8 + r;
    int col0 = 2 * w2i;

    float mt = (h > 0)       ? 1.f : 0.f;
    float mb = (h < HH - 1)  ? 1.f : 0.f;
    float ml = (col0 > 0)    ? 1.f : 0.f;
    float mr = (col0 + 2 < WW) ? 1.f : 0.f;
    int y0 = (h > 0) ? h - 1 : 0;
    int y2 = (h < HH - 1) ? h + 1 : HH - 1;
    int cl = (col0 > 0) ? col0 - 1 : 0;
    int cr = (col0 + 2 < WW) ? col0 + 2 : WW - 1;

    float acc[5][2];
    #pragma unroll
    for (int k = 0; k < 5; ++k) { acc[k][0] = 0.f; acc[k][1] = 0.f; }

    const float* xb = x + ((size_t)b * CC + cs * CPER) * (HH * WW);
    const float* wb = w1t + ((size_t)kcg * CC + cs * CPER) * 45;

    #pragma unroll 2
    for (int c = 0; c < CPER; ++c) {
        const float* xc = xb + c * (HH * WW);
        const float* r0p = xc + y0 * WW;
        const float* r1p = xc + h  * WW;
        const float* r2p = xc + y2 * WW;

        float2 v0 = *(const float2*)(r0p + col0);
        float2 v1 = *(const float2*)(r1p + col0);
        float2 v2 = *(const float2*)(r2p + col0);
        float l0 = r0p[cl], l1 = r1p[cl], l2 = r2p[cl];
        float q0 = r0p[cr], q1 = r1p[cr], q2 = r2p[cr];

        v0.x *= mt; v0.y *= mt; l0 *= mt * ml; q0 *= mt * mr;
        l1 *= ml; q1 *= mr;
        v2.x *= mb; v2.y *= mb; l2 *= mb * ml; q2 *= mb * mr;

        const float* wc = wb + (size_t)c * 45;   // 45 contiguous dwords
        #pragma unroll
        for (int kci = 0; kci < 5; ++kci) {
            const float* wk = wc + kci * 9;
            float w0 = wk[0], w1v = wk[1], w2v = wk[2];
            float w3 = wk[3], w4v = wk[4], w5v = wk[5];
            float w6 = wk[6], w7v = wk[7], w8v = wk[8];
            acc[kci][0] += l0   * w0 + v0.x * w1v + v0.y * w2v
                         + l1   * w3 + v1.x * w4v + v1.y * w5v
                         + l2   * w6 + v2.x * w7v + v2.y * w8v;
            acc[kci][1] += v0.x * w0 + v0.y * w1v + q0   * w2v
                         + v1.x * w3 + v1.y * w4v + q1   * w5v
                         + v2.x * w6 + v2.y * w7v + q2   * w8v;
        }
    }

    float* kb = kwsP + ((size_t)(cs * BB + b) * KK + kcg * 5) * (HH * WW)
                     + h * WW + col0;
    #pragma unroll
    for (int kci = 0; kci < 5; ++kci)
        *(float2*)(kb + (size_t)kci * (HH * WW)) = make_float2(acc[kci][0], acc[kci][1]);
}

// ---------------------------------------------------------------------------
// Kernel 2: fused softmax + local attention (register-held probs) +
//           MFMA 128x16 GEMM (bf16) + 2x2-replicated write.
// grid: 4(b)*64(h)*4(wq) = 1024 blocks of 256 threads.
// ---------------------------------------------------------------------------
__global__ __launch_bounds__(256) void fused_kernel(
        const float* __restrict__ x,
        const unsigned short* __restrict__ w2o,
        const float* __restrict__ b1,
        const float* __restrict__ b2,
        const float* __restrict__ kwsP,
        float* __restrict__ out) {
    __shared__ float pk[KK * 16];                  // softmax probs  (1.6 KB)
    __shared__ float xld[32 * 5 * 24];             // x tile         (15.4 KB)
    __shared__ unsigned short sKT[16 * 136];       // s bf16 [px][c] (4.25 KB)

    int bid = blockIdx.x;
    int wq = bid & 3;
    int h  = (bid >> 2) & 63;
    int b  = bid >> 8;
    int t  = threadIdx.x;

    // ---- Phase 1: sum NCS conv1 partials + bias -> logits ----
    for (int i = t; i < KK * 16; i += 256) {
        int kk = i >> 4, px = i & 15;
        size_t o0 = ((size_t)b * KK + kk) * (HH * WW) + h * WW + wq * 16 + px;
        const size_t sl = (size_t)BB * KK * HH * WW;
        pk[i] = kwsP[o0] + kwsP[o0 + sl] + kwsP[o0 + 2 * sl] + kwsP[o0 + 3 * sl]
              + b1[kk];
    }
    __syncthreads();

    if (t < 16) {
        float mx = -1e30f;
        for (int k = 0; k < KK; ++k) mx = fmaxf(mx, pk[k * 16 + t]);
        float s = 0.f;
        for (int k = 0; k < KK; ++k) {
            float e = __expf(pk[k * 16 + t] - mx);
            pk[k * 16 + t] = e;
            s += e;
        }
        float inv = 1.f / s;
        for (int k = 0; k < KK; ++k) pk[k * 16 + t] *= inv;
    }
    __syncthreads();

    // ---- Phase 2: s[c][px] = sum_tap pr[tap] * xpad[c][...] ----
    // thread = (px = t&15, clane = t>>4); probs hoisted to registers ONCE.
    int px = t & 15, clane = t >> 4;
    float pr[KK];
    #pragma unroll
    for (int k = 0; k < KK; ++k) pr[k] = pk[k * 16 + px];

    const float* xb = x + (size_t)(b * CC) * (HH * WW);
    for (int ch = 0; ch < 4; ++ch) {               // 4 chunks of 32 c
        __syncthreads();
        for (int i = t; i < 3200; i += 256) {
            int c   = i / 100;
            int rem = i - c * 100;
            int di  = rem / 20;
            int col = rem - di * 20;
            int y  = h + di - 2;
            int xc = wq * 16 + col - 2;
            float v = 0.f;
            if (y >= 0 && y < HH && xc >= 0 && xc < WW)
                v = xb[(size_t)(ch * 32 + c) * (HH * WW) + y * WW + xc];
            xld[(c * 5 + di) * 24 + col] = v;
        }
        __syncthreads();

        #pragma unroll
        for (int half = 0; half < 2; ++half) {     // c = chunk*32 + clane(+16)
            int cl16 = clane + half * 16;
            float a = 0.f;
            const float* xr = &xld[cl16 * 120];
            #pragma unroll
            for (int di = 0; di < 5; ++di) {
                float xv[5];
                #pragma unroll
                for (int j = 0; j < 5; ++j) xv[j] = xr[di * 24 + px + j];
                #pragma unroll
                for (int dj = 0; dj < 5; ++dj)
                    a += pr[di * 5 + dj] * xv[dj];
            }
            sKT[px * 136 + ch * 32 + cl16] = f32_to_bf16(a);
        }
    }
    __syncthreads();

    // ---- Phase 3: MFMA. C[o][px] = sum_c W2s[o][c] * s[c][px] ----
    // wave wv handles o-tiles {wv*32, wv*32+16}; K = 128 in 4 steps of 32.
    int lane = t & 63;
    int wv   = t >> 6;
    int fpx  = lane & 15;          // A-row m / B-col n / D-col
    int quad = lane >> 4;

    floatx4 acc0 = {0.f, 0.f, 0.f, 0.f};
    floatx4 acc1 = {0.f, 0.f, 0.f, 0.f};
    #pragma unroll
    for (int ks = 0; ks < 4; ++ks) {
        short8 bfrag = *(const short8*)&sKT[fpx * 136 + ks * 32 + quad * 8];
        short8 a0 = *(const short8*)&w2o[(size_t)(wv * 32 + fpx) * CC
                                         + ks * 32 + quad * 8];
        short8 a1 = *(const short8*)&w2o[(size_t)(wv * 32 + 16 + fpx) * CC
                                         + ks * 32 + quad * 8];
        acc0 = __builtin_amdgcn_mfma_f32_16x16x32_bf16(a0, bfrag, acc0, 0, 0, 0);
        acc1 = __builtin_amdgcn_mfma_f32_16x16x32_bf16(a1, bfrag, acc1, 0, 0, 0);
    }

    // ---- epilogue: D[row=quad*4+reg][col=fpx] + b2, 2x2-replicated write ----
    float* ob = out + (size_t)(b * OUTC) * (4 * HH * WW);
    int y0   = 2 * h;
    int xcol = 2 * (wq * 16 + fpx);
    #pragma unroll
    for (int tile = 0; tile < 2; ++tile) {
        #pragma unroll
        for (int reg = 0; reg < 4; ++reg) {
            int o = wv * 32 + tile * 16 + quad * 4 + reg;
            float v = (tile ? acc1[reg] : acc0[reg]) + b2[o];
            float2 v2 = make_float2(v, v);
            float* r0 = ob + ((size_t)o * (2 * HH) + y0) * (2 * WW) + xcol;
            *(float2*)(r0)          = v2;
            *(float2*)(r0 + 2 * WW) = v2;
        }
    }
}

// ---------------------------------------------------------------------------
extern "C" void kernel_launch(void* const* d_in, const int* in_sizes, int n_in,
                              void* d_out, int out_size, void* d_ws, size_t ws_size,
                              hipStream_t stream) {
    const float* x  = (const float*)d_in[0];
    const float* w1 = (const float*)d_in[1];
    const float* b1 = (const float*)d_in[2];
    const float* w2 = (const float*)d_in[3];
    const float* b2 = (const float*)d_in[4];
    float* out = (float*)d_out;

    const size_t slab = (size_t)BB * KK * HH * WW;        // 409600 floats/cs
    float* kwsP = (float*)d_ws;                           // 4 slabs: 6.55 MB
    unsigned short* w2o = (unsigned short*)(kwsP + NCS * slab);    // 32 KB
    float* w1t = (float*)(w2o + (size_t)OUTC * CC);                // 115 KB

    prep_kernel<<<(16384 + 28800 + 255) / 256, 256, 0, stream>>>(w2, w1, w2o, w1t);
    conv1_kernel<<<BB * 8 * NCS * 5, 256, 0, stream>>>(x, w1t, kwsP);
    fused_kernel<<<BB * HH * 4, 256, 0, stream>>>(x, w2o, b1, b2, kwsP, out);
}

// Round 8
// 134.061 us; speedup vs baseline: 1.5566x; 1.0113x over previous
//
#include <hip/hip_runtime.h>
#include <math.h>

// Problem constants
#define BB   4
#define CC   128
#define HH   64
#define WW   64
#define OUTC 128
#define LW   5
#define KK   25   // LW*LW
#define NCS  8    // conv1 c-split count
#define CPER 16   // channels per split

typedef __attribute__((ext_vector_type(8))) short short8;   // 8 bf16
typedef __attribute__((ext_vector_type(4))) float floatx4;  // MFMA acc

__device__ __forceinline__ unsigned short f32_to_bf16(float v) {
    unsigned int u = __float_as_uint(v);
    u += 0x7fffu + ((u >> 16) & 1u);          // RNE
    return (unsigned short)(u >> 16);
}

// ---------------------------------------------------------------------------
// Kernel 0 (prep): two jobs in one launch.
//  i < 16384:  w2o[o][c] = bf16( sum_{r} w2[o, c*4+r] )      (o-major)
//  else:       w1t[kcg][c][kci][j] = w1[(kcg*5+kci)][c][j]   (45 contig / c)
// ---------------------------------------------------------------------------
__global__ void prep_kernel(const float* __restrict__ w2,
                            const float* __restrict__ w1,
                            unsigned short* __restrict__ w2o,
                            float* __restrict__ w1t) {
    int i = blockIdx.x * 256 + threadIdx.x;
    if (i < 16384) {
        int o = i >> 7, c = i & 127;
        const float* p = w2 + o * (4 * CC) + c * 4;
        w2o[o * CC + c] = f32_to_bf16(p[0] + p[1] + p[2] + p[3]);
    } else if (i < 16384 + 28800) {
        int j  = i - 16384;
        int jj = j % 9;
        int r  = j / 9;
        int kci = r % 5;  r /= 5;
        int c   = r % 128;
        int kcg = r / 128;
        w1t[j] = w1[(size_t)((kcg * 5 + kci) * CC + c) * 9 + jj];
    }
}

// ---------------------------------------------------------------------------
// Kernel 1: conv1 3x3 SAME. No LDS/barriers; contiguous 45 weight dwords/c
// (bulk s_load). grid 4(b)*8(ht)*8(cs)*5(kcg) = 1280 blocks, 256 threads
// (20 waves/CU for latency hiding). thread: 2 px.
// Output: per-cs partial slabs kwsP[cs][b][kc][h][w].
// ---------------------------------------------------------------------------
__global__ __launch_bounds__(256) void conv1_kernel(
        const float* __restrict__ x,
        const float* __restrict__ w1t,
        float* __restrict__ kwsP) {
    int bid = blockIdx.x;
    int kcg  = bid % 5;
    int rest = bid / 5;
    int cs   = rest & 7;
    rest >>= 3;
    int ht = rest & 7;
    int b  = rest >> 3;

    int t  = threadIdx.x;
    int w2i = t & 31;
    int r   = t >> 5;
    int h   = ht * 8 + r;
    int col0 = 2 * w2i;

    float mt = (h > 0)       ? 1.f : 0.f;
    float mb = (h < HH - 1)  ? 1.f : 0.f;
    float ml = (col0 > 0)    ? 1.f : 0.f;
    float mr = (col0 + 2 < WW) ? 1.f : 0.f;
    int y0 = (h > 0) ? h - 1 : 0;
    int y2 = (h < HH - 1) ? h + 1 : HH - 1;
    int cl = (col0 > 0) ? col0 - 1 : 0;
    int cr = (col0 + 2 < WW) ? col0 + 2 : WW - 1;

    float acc[5][2];
    #pragma unroll
    for (int k = 0; k < 5; ++k) { acc[k][0] = 0.f; acc[k][1] = 0.f; }

    const float* xb = x + ((size_t)b * CC + cs * CPER) * (HH * WW);
    const float* wb = w1t + ((size_t)kcg * CC + cs * CPER) * 45;

    #pragma unroll 4
    for (int c = 0; c < CPER; ++c) {
        const float* xc = xb + c * (HH * WW);
        const float* r0p = xc + y0 * WW;
        const float* r1p = xc + h  * WW;
        const float* r2p = xc + y2 * WW;

        float2 v0 = *(const float2*)(r0p + col0);
        float2 v1 = *(const float2*)(r1p + col0);
        float2 v2 = *(const float2*)(r2p + col0);
        float l0 = r0p[cl], l1 = r1p[cl], l2 = r2p[cl];
        float q0 = r0p[cr], q1 = r1p[cr], q2 = r2p[cr];

        v0.x *= mt; v0.y *= mt; l0 *= mt * ml; q0 *= mt * mr;
        l1 *= ml; q1 *= mr;
        v2.x *= mb; v2.y *= mb; l2 *= mb * ml; q2 *= mb * mr;

        const float* wc = wb + (size_t)c * 45;   // 45 contiguous dwords
        #pragma unroll
        for (int kci = 0; kci < 5; ++kci) {
            const float* wk = wc + kci * 9;
            float w0 = wk[0], w1v = wk[1], w2v = wk[2];
            float w3 = wk[3], w4v = wk[4], w5v = wk[5];
            float w6 = wk[6], w7v = wk[7], w8v = wk[8];
            acc[kci][0] += l0   * w0 + v0.x * w1v + v0.y * w2v
                         + l1   * w3 + v1.x * w4v + v1.y * w5v
                         + l2   * w6 + v2.x * w7v + v2.y * w8v;
            acc[kci][1] += v0.x * w0 + v0.y * w1v + q0   * w2v
                         + v1.x * w3 + v1.y * w4v + q1   * w5v
                         + v2.x * w6 + v2.y * w7v + q2   * w8v;
        }
    }

    float* kb = kwsP + ((size_t)(cs * BB + b) * KK + kcg * 5) * (HH * WW)
                     + h * WW + col0;
    #pragma unroll
    for (int kci = 0; kci < 5; ++kci)
        *(float2*)(kb + (size_t)kci * (HH * WW)) = make_float2(acc[kci][0], acc[kci][1]);
}

// ---------------------------------------------------------------------------
// Kernel 2: fused softmax + local attention (px-pair, b64 LDS reads) +
//           MFMA 128x16 GEMM (bf16) + 2x2-replicated write.
// grid: 4(b)*64(h)*4(wq) = 1024 blocks of 256 threads.
// ---------------------------------------------------------------------------
__global__ __launch_bounds__(256) void fused_kernel(
        const float* __restrict__ x,
        const unsigned short* __restrict__ w2o,
        const float* __restrict__ b1,
        const float* __restrict__ b2,
        const float* __restrict__ kwsP,
        float* __restrict__ out) {
    __shared__ float pk[KK * 16];                  // softmax probs  (1.6 KB)
    __shared__ float xld[32 * 5 * 24];             // x tile         (15.4 KB)
    __shared__ unsigned short sKT[16 * 136];       // s bf16 [px][c] (4.25 KB)

    int bid = blockIdx.x;
    int wq = bid & 3;
    int h  = (bid >> 2) & 63;
    int b  = bid >> 8;
    int t  = threadIdx.x;

    // ---- Phase 1: sum NCS conv1 partials + bias -> logits ----
    const size_t sl = (size_t)BB * KK * HH * WW;
    for (int i = t; i < KK * 16; i += 256) {
        int kk = i >> 4, px = i & 15;
        size_t o0 = ((size_t)b * KK + kk) * (HH * WW) + h * WW + wq * 16 + px;
        float v = b1[kk];
        #pragma unroll
        for (int cs = 0; cs < NCS; ++cs) v += kwsP[o0 + cs * sl];
        pk[i] = v;
    }
    __syncthreads();

    if (t < 16) {
        float mx = -1e30f;
        for (int k = 0; k < KK; ++k) mx = fmaxf(mx, pk[k * 16 + t]);
        float s = 0.f;
        for (int k = 0; k < KK; ++k) {
            float e = __expf(pk[k * 16 + t] - mx);
            pk[k * 16 + t] = e;
            s += e;
        }
        float inv = 1.f / s;
        for (int k = 0; k < KK; ++k) pk[k * 16 + t] *= inv;
    }
    __syncthreads();

    // ---- Phase 2: s[c][px] = sum_tap p[tap][px] * xpad[c][...] ----
    // thread = (pp = t&7 -> pixels {2pp,2pp+1}, clane = t>>3 -> 1 c per chunk)
    int pp = t & 7, clane = t >> 3;
    float p0[KK], p1[KK];
    #pragma unroll
    for (int k = 0; k < KK; ++k) {
        p0[k] = pk[k * 16 + 2 * pp];
        p1[k] = pk[k * 16 + 2 * pp + 1];
    }

    const float* xb = x + (size_t)(b * CC) * (HH * WW);
    for (int ch = 0; ch < 4; ++ch) {               // 4 chunks of 32 c
        __syncthreads();
        for (int i = t; i < 3200; i += 256) {
            int c   = i / 100;
            int rem = i - c * 100;
            int di  = rem / 20;
            int col = rem - di * 20;
            int y  = h + di - 2;
            int xc = wq * 16 + col - 2;
            float v = 0.f;
            if (y >= 0 && y < HH && xc >= 0 && xc < WW)
                v = xb[(size_t)(ch * 32 + c) * (HH * WW) + y * WW + xc];
            xld[(c * 5 + di) * 24 + col] = v;
        }
        __syncthreads();

        float a0 = 0.f, a1 = 0.f;
        const float* xr = &xld[clane * 120 + 2 * pp];
        #pragma unroll
        for (int di = 0; di < 5; ++di) {
            float2 x01 = *(const float2*)(xr + di * 24);       // 8B-aligned
            float2 x23 = *(const float2*)(xr + di * 24 + 2);
            float2 x45 = *(const float2*)(xr + di * 24 + 4);
            const float* q0 = &p0[di * 5];
            const float* q1 = &p1[di * 5];
            a0 += q0[0] * x01.x + q0[1] * x01.y + q0[2] * x23.x
                + q0[3] * x23.y + q0[4] * x45.x;
            a1 += q1[0] * x01.y + q1[1] * x23.x + q1[2] * x23.y
                + q1[3] * x45.x + q1[4] * x45.y;
        }
        int c = ch * 32 + clane;
        sKT[(2 * pp) * 136 + c]     = f32_to_bf16(a0);
        sKT[(2 * pp + 1) * 136 + c] = f32_to_bf16(a1);
    }
    __syncthreads();

    // ---- Phase 3: MFMA. C[o][px] = sum_c W2s[o][c] * s[c][px] ----
    int lane = t & 63;
    int wv   = t >> 6;
    int fpx  = lane & 15;
    int quad = lane >> 4;

    floatx4 acc0 = {0.f, 0.f, 0.f, 0.f};
    floatx4 acc1 = {0.f, 0.f, 0.f, 0.f};
    #pragma unroll
    for (int ks = 0; ks < 4; ++ks) {
        short8 bfrag = *(const short8*)&sKT[fpx * 136 + ks * 32 + quad * 8];
        short8 a0 = *(const short8*)&w2o[(size_t)(wv * 32 + fpx) * CC
                                         + ks * 32 + quad * 8];
        short8 a1 = *(const short8*)&w2o[(size_t)(wv * 32 + 16 + fpx) * CC
                                         + ks * 32 + quad * 8];
        acc0 = __builtin_amdgcn_mfma_f32_16x16x32_bf16(a0, bfrag, acc0, 0, 0, 0);
        acc1 = __builtin_amdgcn_mfma_f32_16x16x32_bf16(a1, bfrag, acc1, 0, 0, 0);
    }

    // ---- epilogue: D[row=quad*4+reg][col=fpx] + b2, 2x2-replicated write ----
    float* ob = out + (size_t)(b * OUTC) * (4 * HH * WW);
    int y0   = 2 * h;
    int xcol = 2 * (wq * 16 + fpx);
    #pragma unroll
    for (int tile = 0; tile < 2; ++tile) {
        #pragma unroll
        for (int reg = 0; reg < 4; ++reg) {
            int o = wv * 32 + tile * 16 + quad * 4 + reg;
            float v = (tile ? acc1[reg] : acc0[reg]) + b2[o];
            float2 v2 = make_float2(v, v);
            float* r0 = ob + ((size_t)o * (2 * HH) + y0) * (2 * WW) + xcol;
            *(float2*)(r0)          = v2;
            *(float2*)(r0 + 2 * WW) = v2;
        }
    }
}

// ---------------------------------------------------------------------------
extern "C" void kernel_launch(void* const* d_in, const int* in_sizes, int n_in,
                              void* d_out, int out_size, void* d_ws, size_t ws_size,
                              hipStream_t stream) {
    const float* x  = (const float*)d_in[0];
    const float* w1 = (const float*)d_in[1];
    const float* b1 = (const float*)d_in[2];
    const float* w2 = (const float*)d_in[3];
    const float* b2 = (const float*)d_in[4];
    float* out = (float*)d_out;

    const size_t slab = (size_t)BB * KK * HH * WW;        // 409600 floats/cs
    float* kwsP = (float*)d_ws;                           // 8 slabs: 13.1 MB
    unsigned short* w2o = (unsigned short*)(kwsP + NCS * slab);    // 32 KB
    float* w1t = (float*)(w2o + (size_t)OUTC * CC);                // 115 KB

    prep_kernel<<<(16384 + 28800 + 255) / 256, 256, 0, stream>>>(w2, w1, w2o, w1t);
    conv1_kernel<<<BB * 8 * NCS * 5, 256, 0, stream>>>(x, w1t, kwsP);
    fused_kernel<<<BB * HH * 4, 256, 0, stream>>>(x, w2o, b1, b2, kwsP, out);
}

// Round 9
// 133.505 us; speedup vs baseline: 1.5631x; 1.0042x over previous
//
#include <hip/hip_runtime.h>
#include <math.h>

// Problem constants
#define BB   4
#define CC   128
#define HH   64
#define WW   64
#define OUTC 128
#define LW   5
#define KK   25   // LW*LW
#define NCS  8    // conv1 c-split count
#define CPER 16   // channels per split

typedef __attribute__((ext_vector_type(8))) short short8;   // 8 bf16
typedef __attribute__((ext_vector_type(4))) float floatx4;  // MFMA acc

__device__ __forceinline__ unsigned short f32_to_bf16(float v) {
    unsigned int u = __float_as_uint(v);
    u += 0x7fffu + ((u >> 16) & 1u);          // RNE
    return (unsigned short)(u >> 16);
}

// ---------------------------------------------------------------------------
// Kernel 0 (prep): two jobs in one launch.
//  i < 16384:  w2o[o][c] = bf16( sum_{r} w2[o, c*4+r] )      (o-major)
//  else:       w1t[kcg][c][kci][j] = w1[(kcg*5+kci)][c][j]   (45 contig / c)
// ---------------------------------------------------------------------------
__global__ void prep_kernel(const float* __restrict__ w2,
                            const float* __restrict__ w1,
                            unsigned short* __restrict__ w2o,
                            float* __restrict__ w1t) {
    int i = blockIdx.x * 256 + threadIdx.x;
    if (i < 16384) {
        int o = i >> 7, c = i & 127;
        const float* p = w2 + o * (4 * CC) + c * 4;
        w2o[o * CC + c] = f32_to_bf16(p[0] + p[1] + p[2] + p[3]);
    } else if (i < 16384 + 28800) {
        int j  = i - 16384;
        int jj = j % 9;
        int r  = j / 9;
        int kci = r % 5;  r /= 5;
        int c   = r % 128;
        int kcg = r / 128;
        w1t[j] = w1[(size_t)((kcg * 5 + kci) * CC + c) * 9 + jj];
    }
}

// ---------------------------------------------------------------------------
// Kernel 1: conv1 3x3 SAME. No LDS/barriers; contiguous 45 weight dwords/c.
// grid 4(b)*8(ht)*8(cs)*5(kcg) = 1280 blocks, 256 threads. thread: 2 px.
// __launch_bounds__(256,4): 128-VGPR budget so unroll-4 load batches can
// stay in flight (was VGPR=40 -> serialized VMEM latency, VALUBusy ~20%).
// ---------------------------------------------------------------------------
__global__ __launch_bounds__(256, 4) void conv1_kernel(
        const float* __restrict__ x,
        const float* __restrict__ w1t,
        float* __restrict__ kwsP) {
    int bid = blockIdx.x;
    int kcg  = bid % 5;
    int rest = bid / 5;
    int cs   = rest & 7;
    rest >>= 3;
    int ht = rest & 7;
    int b  = rest >> 3;

    int t  = threadIdx.x;
    int w2i = t & 31;
    int r   = t >> 5;
    int h   = ht * 8 + r;
    int col0 = 2 * w2i;

    float mt = (h > 0)       ? 1.f : 0.f;
    float mb = (h < HH - 1)  ? 1.f : 0.f;
    float ml = (col0 > 0)    ? 1.f : 0.f;
    float mr = (col0 + 2 < WW) ? 1.f : 0.f;
    int y0 = (h > 0) ? h - 1 : 0;
    int y2 = (h < HH - 1) ? h + 1 : HH - 1;
    int cl = (col0 > 0) ? col0 - 1 : 0;
    int cr = (col0 + 2 < WW) ? col0 + 2 : WW - 1;

    float acc[5][2];
    #pragma unroll
    for (int k = 0; k < 5; ++k) { acc[k][0] = 0.f; acc[k][1] = 0.f; }

    const float* xb = x + ((size_t)b * CC + cs * CPER) * (HH * WW);
    const float* wb = w1t + ((size_t)kcg * CC + cs * CPER) * 45;

    #pragma unroll 4
    for (int c = 0; c < CPER; ++c) {
        const float* xc = xb + c * (HH * WW);
        const float* r0p = xc + y0 * WW;
        const float* r1p = xc + h  * WW;
        const float* r2p = xc + y2 * WW;

        float2 v0 = *(const float2*)(r0p + col0);
        float2 v1 = *(const float2*)(r1p + col0);
        float2 v2 = *(const float2*)(r2p + col0);
        float l0 = r0p[cl], l1 = r1p[cl], l2 = r2p[cl];
        float q0 = r0p[cr], q1 = r1p[cr], q2 = r2p[cr];

        v0.x *= mt; v0.y *= mt; l0 *= mt * ml; q0 *= mt * mr;
        l1 *= ml; q1 *= mr;
        v2.x *= mb; v2.y *= mb; l2 *= mb * ml; q2 *= mb * mr;

        const float* wc = wb + (size_t)c * 45;   // 45 contiguous dwords
        #pragma unroll
        for (int kci = 0; kci < 5; ++kci) {
            const float* wk = wc + kci * 9;
            float w0 = wk[0], w1v = wk[1], w2v = wk[2];
            float w3 = wk[3], w4v = wk[4], w5v = wk[5];
            float w6 = wk[6], w7v = wk[7], w8v = wk[8];
            acc[kci][0] += l0   * w0 + v0.x * w1v + v0.y * w2v
                         + l1   * w3 + v1.x * w4v + v1.y * w5v
                         + l2   * w6 + v2.x * w7v + v2.y * w8v;
            acc[kci][1] += v0.x * w0 + v0.y * w1v + q0   * w2v
                         + v1.x * w3 + v1.y * w4v + q1   * w5v
                         + v2.x * w6 + v2.y * w7v + q2   * w8v;
        }
    }

    float* kb = kwsP + ((size_t)(cs * BB + b) * KK + kcg * 5) * (HH * WW)
                     + h * WW + col0;
    #pragma unroll
    for (int kci = 0; kci < 5; ++kci)
        *(float2*)(kb + (size_t)kci * (HH * WW)) = make_float2(acc[kci][0], acc[kci][1]);
}

// ---------------------------------------------------------------------------
// Kernel 2: fused softmax + local attention (batched b64 LDS loads) +
//           MFMA 128x16 GEMM (bf16) + 2x2-replicated write.
// grid: 4(b)*64(h)*4(wq) = 1024 blocks of 256 threads.
// __launch_bounds__(256,4): 128-VGPR budget (was 32) so the 15 independent
// ds_read_b64 per chunk can all be in flight under one lgkmcnt window.
// ---------------------------------------------------------------------------
__global__ __launch_bounds__(256, 4) void fused_kernel(
        const float* __restrict__ x,
        const unsigned short* __restrict__ w2o,
        const float* __restrict__ b1,
        const float* __restrict__ b2,
        const float* __restrict__ kwsP,
        float* __restrict__ out) {
    __shared__ float pk[KK * 16];                  // softmax probs  (1.6 KB)
    __shared__ float xld[32 * 5 * 24];             // x tile         (15.4 KB)
    __shared__ unsigned short sKT[16 * 136];       // s bf16 [px][c] (4.25 KB)

    int bid = blockIdx.x;
    int wq = bid & 3;
    int h  = (bid >> 2) & 63;
    int b  = bid >> 8;
    int t  = threadIdx.x;

    // ---- Phase 1: sum NCS conv1 partials + bias -> logits ----
    const size_t sl = (size_t)BB * KK * HH * WW;
    for (int i = t; i < KK * 16; i += 256) {
        int kk = i >> 4, px = i & 15;
        size_t o0 = ((size_t)b * KK + kk) * (HH * WW) + h * WW + wq * 16 + px;
        float v = b1[kk];
        #pragma unroll
        for (int cs = 0; cs < NCS; ++cs) v += kwsP[o0 + cs * sl];
        pk[i] = v;
    }
    __syncthreads();

    if (t < 16) {
        float mx = -1e30f;
        for (int k = 0; k < KK; ++k) mx = fmaxf(mx, pk[k * 16 + t]);
        float s = 0.f;
        for (int k = 0; k < KK; ++k) {
            float e = __expf(pk[k * 16 + t] - mx);
            pk[k * 16 + t] = e;
            s += e;
        }
        float inv = 1.f / s;
        for (int k = 0; k < KK; ++k) pk[k * 16 + t] *= inv;
    }
    __syncthreads();

    // ---- Phase 2: s[c][px] = sum_tap p[tap][px] * xpad[c][...] ----
    // thread = (pp = t&7 -> pixels {2pp,2pp+1}, clane = t>>3 -> 1 c per chunk)
    int pp = t & 7, clane = t >> 3;
    float p0[KK], p1[KK];
    #pragma unroll
    for (int k = 0; k < KK; ++k) {
        p0[k] = pk[k * 16 + 2 * pp];
        p1[k] = pk[k * 16 + 2 * pp + 1];
    }

    const float* xb = x + (size_t)(b * CC) * (HH * WW);
    for (int ch = 0; ch < 4; ++ch) {               // 4 chunks of 32 c
        __syncthreads();
        for (int i = t; i < 3200; i += 256) {
            int c   = i / 100;
            int rem = i - c * 100;
            int di  = rem / 20;
            int col = rem - di * 20;
            int y  = h + di - 2;
            int xc = wq * 16 + col - 2;
            float v = 0.f;
            if (y >= 0 && y < HH && xc >= 0 && xc < WW)
                v = xb[(size_t)(ch * 32 + c) * (HH * WW) + y * WW + xc];
            xld[(c * 5 + di) * 24 + col] = v;
        }
        __syncthreads();

        // batch all 15 b64 loads first, then the 50 FMAs
        const float* xr = &xld[clane * 120 + 2 * pp];
        float2 xv[15];
        #pragma unroll
        for (int di = 0; di < 5; ++di) {
            xv[di * 3 + 0] = *(const float2*)(xr + di * 24);
            xv[di * 3 + 1] = *(const float2*)(xr + di * 24 + 2);
            xv[di * 3 + 2] = *(const float2*)(xr + di * 24 + 4);
        }
        float a0 = 0.f, a1 = 0.f;
        #pragma unroll
        for (int di = 0; di < 5; ++di) {
            const float* q0 = &p0[di * 5];
            const float* q1 = &p1[di * 5];
            float2 x01 = xv[di * 3 + 0];
            float2 x23 = xv[di * 3 + 1];
            float2 x45 = xv[di * 3 + 2];
            a0 += q0[0] * x01.x + q0[1] * x01.y + q0[2] * x23.x
                + q0[3] * x23.y + q0[4] * x45.x;
            a1 += q1[0] * x01.y + q1[1] * x23.x + q1[2] * x23.y
                + q1[3] * x45.x + q1[4] * x45.y;
        }
        int c = ch * 32 + clane;
        sKT[(2 * pp) * 136 + c]     = f32_to_bf16(a0);
        sKT[(2 * pp + 1) * 136 + c] = f32_to_bf16(a1);
    }
    __syncthreads();

    // ---- Phase 3: MFMA. C[o][px] = sum_c W2s[o][c] * s[c][px] ----
    int lane = t & 63;
    int wv   = t >> 6;
    int fpx  = lane & 15;
    int quad = lane >> 4;

    floatx4 acc0 = {0.f, 0.f, 0.f, 0.f};
    floatx4 acc1 = {0.f, 0.f, 0.f, 0.f};
    #pragma unroll
    for (int ks = 0; ks < 4; ++ks) {
        short8 bfrag = *(const short8*)&sKT[fpx * 136 + ks * 32 + quad * 8];
        short8 a0 = *(const short8*)&w2o[(size_t)(wv * 32 + fpx) * CC
                                         + ks * 32 + quad * 8];
        short8 a1 = *(const short8*)&w2o[(size_t)(wv * 32 + 16 + fpx) * CC
                                         + ks * 32 + quad * 8];
        acc0 = __builtin_amdgcn_mfma_f32_16x16x32_bf16(a0, bfrag, acc0, 0, 0, 0);
        acc1 = __builtin_amdgcn_mfma_f32_16x16x32_bf16(a1, bfrag, acc1, 0, 0, 0);
    }

    // ---- epilogue: D[row=quad*4+reg][col=fpx] + b2, 2x2-replicated write ----
    float* ob = out + (size_t)(b * OUTC) * (4 * HH * WW);
    int y0   = 2 * h;
    int xcol = 2 * (wq * 16 + fpx);
    #pragma unroll
    for (int tile = 0; tile < 2; ++tile) {
        #pragma unroll
        for (int reg = 0; reg < 4; ++reg) {
            int o = wv * 32 + tile * 16 + quad * 4 + reg;
            float v = (tile ? acc1[reg] : acc0[reg]) + b2[o];
            float2 v2 = make_float2(v, v);
            float* r0 = ob + ((size_t)o * (2 * HH) + y0) * (2 * WW) + xcol;
            *(float2*)(r0)          = v2;
            *(float2*)(r0 + 2 * WW) = v2;
        }
    }
}

// ---------------------------------------------------------------------------
extern "C" void kernel_launch(void* const* d_in, const int* in_sizes, int n_in,
                              void* d_out, int out_size, void* d_ws, size_t ws_size,
                              hipStream_t stream) {
    const float* x  = (const float*)d_in[0];
    const float* w1 = (const float*)d_in[1];
    const float* b1 = (const float*)d_in[2];
    const float* w2 = (const float*)d_in[3];
    const float* b2 = (const float*)d_in[4];
    float* out = (float*)d_out;

    const size_t slab = (size_t)BB * KK * HH * WW;        // 409600 floats/cs
    float* kwsP = (float*)d_ws;                           // 8 slabs: 13.1 MB
    unsigned short* w2o = (unsigned short*)(kwsP + NCS * slab);    // 32 KB
    float* w1t = (float*)(w2o + (size_t)OUTC * CC);                // 115 KB

    prep_kernel<<<(16384 + 28800 + 255) / 256, 256, 0, stream>>>(w2, w1, w2o, w1t);
    conv1_kernel<<<BB * 8 * NCS * 5, 256, 0, stream>>>(x, w1t, kwsP);
    fused_kernel<<<BB * HH * 4, 256, 0, stream>>>(x, w2o, b1, b2, kwsP, out);
}